// Round 1
// baseline (589.017 us; speedup 1.0000x reference)
//
#include <hip/hip_runtime.h>
#include <cstdint>
#include <cstddef>

typedef __attribute__((ext_vector_type(8))) short bf16x8;
typedef __attribute__((ext_vector_type(4))) float f32x4;
typedef __attribute__((ext_vector_type(8))) unsigned short ushort8;

__device__ __forceinline__ unsigned short f2bf(float f) {
  union { float f; unsigned int u; } x; x.f = f;
  unsigned int r = (x.u + 0x7fffu + ((x.u >> 16) & 1u)) >> 16;  // RNE
  return (unsigned short)r;
}

// ---------------------------------------------------------------------------
// K0: convert W3 [128,4096] f32 -> bf16 (reused 1024x by K2, convert once)
// ---------------------------------------------------------------------------
__global__ __launch_bounds__(256) void k0_cvt(const float* __restrict__ W3,
                                              unsigned short* __restrict__ W3b) {
  int e = (blockIdx.x * 256 + threadIdx.x) * 8;  // 256 blocks * 256 thr * 8 = 524288
  float4 f0 = *(const float4*)(W3 + e);
  float4 f1 = *(const float4*)(W3 + e + 4);
  ushort8 v;
  v[0] = f2bf(f0.x); v[1] = f2bf(f0.y); v[2] = f2bf(f0.z); v[3] = f2bf(f0.w);
  v[4] = f2bf(f1.x); v[5] = f2bf(f1.y); v[6] = f2bf(f1.z); v[7] = f2bf(f1.w);
  *(ushort8*)(W3b + e) = v;
}

// ---------------------------------------------------------------------------
// Kconst: const[k] = dot(W3[k,:], b2) + b3[k]   (128 x 4096 dot, fp32)
// ---------------------------------------------------------------------------
__global__ __launch_bounds__(64) void kconst(const float* __restrict__ W3,
                                             const float* __restrict__ b2,
                                             const float* __restrict__ b3,
                                             float* __restrict__ constv) {
  int k = blockIdx.x;
  int lane = threadIdx.x;
  float s = 0.f;
  for (int j = lane; j < 4096; j += 64) s += W3[k * 4096 + j] * b2[j];
#pragma unroll
  for (int m = 1; m < 64; m <<= 1) s += __shfl_xor(s, m, 64);
  if (lane == 0) constv[k] = s + b3[k];
}

// ---------------------------------------------------------------------------
// K1: o = x @ W1^T + b1 (fp32 vector GEMM), fused per-256-segment argmax.
// Block = 64 rows x 256 cols (one full segment). 256 threads,
// thread tile 8b x 8c (c split as cIdx*4+u and 128+cIdx*4+u for clean b128).
// ---------------------------------------------------------------------------
__global__ __launch_bounds__(256) void k1_gemm_argmax(
    const float* __restrict__ x, const float* __restrict__ W1,
    const float* __restrict__ b1, int* __restrict__ idxbuf) {
  __shared__ float xs[16][68];     // [k][row], pad 68 -> 2-way-max store conflicts, 16B aligned rows
  __shared__ float w1s[16][256];   // [k][col]
  const int t = threadIdx.x;
  const int r0 = blockIdx.x * 64;
  const int seg = blockIdx.y;
  const int c0 = seg * 256;
  const int bIdx = t >> 5;   // 0..7  -> rows bIdx*8..+7
  const int cIdx = t & 31;   // 0..31 -> cols cIdx*4+u, 128+cIdx*4+u

  float acc[8][8];
  {
    float binit[8];
#pragma unroll
    for (int v = 0; v < 2; v++)
#pragma unroll
      for (int u = 0; u < 4; u++) binit[v * 4 + u] = b1[c0 + v * 128 + cIdx * 4 + u];
#pragma unroll
    for (int i = 0; i < 8; i++)
#pragma unroll
      for (int j = 0; j < 8; j++) acc[i][j] = binit[j];
  }

  const int xrow = t >> 2, xkq = t & 3;
  for (int kb = 0; kb < 128; kb += 16) {
    __syncthreads();
    {
      float4 f = *(const float4*)(x + (r0 + xrow) * 128 + kb + xkq * 4);
      xs[xkq * 4 + 0][xrow] = f.x;
      xs[xkq * 4 + 1][xrow] = f.y;
      xs[xkq * 4 + 2][xrow] = f.z;
      xs[xkq * 4 + 3][xrow] = f.w;
    }
#pragma unroll
    for (int q = 0; q < 4; q++) {
      float4 f = *(const float4*)(W1 + (c0 + t) * 128 + kb + q * 4);
      w1s[q * 4 + 0][t] = f.x;
      w1s[q * 4 + 1][t] = f.y;
      w1s[q * 4 + 2][t] = f.z;
      w1s[q * 4 + 3][t] = f.w;
    }
    __syncthreads();
#pragma unroll
    for (int kk = 0; kk < 16; kk++) {
      float a[8], bb[8];
      *(float4*)&a[0] = *(const float4*)&xs[kk][bIdx * 8];
      *(float4*)&a[4] = *(const float4*)&xs[kk][bIdx * 8 + 4];
      *(float4*)&bb[0] = *(const float4*)&w1s[kk][cIdx * 4];
      *(float4*)&bb[4] = *(const float4*)&w1s[kk][128 + cIdx * 4];
#pragma unroll
      for (int i = 0; i < 8; i++)
#pragma unroll
        for (int j = 0; j < 8; j++) acc[i][j] = fmaf(a[i], bb[j], acc[i][j]);
    }
  }

  // per-row argmax across the segment; numpy semantics: first (lowest c) max wins
#pragma unroll
  for (int i = 0; i < 8; i++) {
    float mv = acc[i][0];
    int mi = cIdx * 4;
#pragma unroll
    for (int j = 1; j < 8; j++) {
      int c = (j < 4) ? (cIdx * 4 + j) : (128 + cIdx * 4 + (j - 4));
      if (acc[i][j] > mv) { mv = acc[i][j]; mi = c; }
    }
#pragma unroll
    for (int m = 1; m <= 16; m <<= 1) {
      float ov = __shfl_xor(mv, m, 64);
      int oi = __shfl_xor(mi, m, 64);
      if (ov > mv || (ov == mv && oi < mi)) { mv = ov; mi = oi; }
    }
    if (cIdx == 0) idxbuf[(r0 + bIdx * 8 + i) * 16 + seg] = mi;
  }
}

// ---------------------------------------------------------------------------
// K2: Mt^partial[c,k] = sum_{j in quarter} W2[j,c] * W3[k,j]  via bf16 MFMA.
// One wave per block: m-tile = 16 c's, n covers all 128 k (8 n-tiles).
// A-frag: A[m=lane&15][kk=q*8+i] = W2[j0+q*8+i][c0+m]  (fp32 load + cvt;
//         quad lanes read 16 consecutive floats -> coalesced 64B lines)
// B-frag: B[n=lane&15][kk=q*8+i] = W3b[n][j0+q*8+i]    (contiguous 16B dwordx4)
// C/D:    D[row=q*4+r][col=lane&15] -> c_local=q*4+r, k=nt*16+(lane&15)
// ---------------------------------------------------------------------------
__global__ __launch_bounds__(64) void k2_mfma(const float* __restrict__ W2,
                                              const unsigned short* __restrict__ W3b,
                                              float* __restrict__ Mp) {
  const int lane = threadIdx.x;
  const int c0 = blockIdx.x * 16;  // 256 c-strips
  const int jq = blockIdx.y;       // 4 K-quarters (split-K for occupancy)
  const int m = lane & 15, q = lane >> 4;
  f32x4 acc[8];
#pragma unroll
  for (int nt = 0; nt < 8; nt++) acc[nt] = (f32x4){0.f, 0.f, 0.f, 0.f};

  for (int it = 0; it < 32; it++) {
    const int j0 = jq * 1024 + it * 32;
    union { bf16x8 v; unsigned short u[8]; } a;
    const float* ap = W2 + (size_t)(j0 + q * 8) * 4096 + c0 + m;
#pragma unroll
    for (int i = 0; i < 8; i++) a.u[i] = f2bf(ap[(size_t)i * 4096]);
#pragma unroll
    for (int nt = 0; nt < 8; nt++) {
      bf16x8 b = *(const bf16x8*)(W3b + (nt * 16 + m) * 4096 + j0 + q * 8);
      acc[nt] = __builtin_amdgcn_mfma_f32_16x16x32_bf16(a.v, b, acc[nt], 0, 0, 0);
    }
  }

  float* out = Mp + ((size_t)jq * 4096 + c0) * 128;
#pragma unroll
  for (int nt = 0; nt < 8; nt++)
#pragma unroll
    for (int r = 0; r < 4; r++)
      out[(q * 4 + r) * 128 + nt * 16 + m] = acc[nt][r];
}

// ---------------------------------------------------------------------------
// K2b: reduce 4 split-K partials -> Mt [4096,128] f32
// ---------------------------------------------------------------------------
__global__ __launch_bounds__(256) void k2b_reduce(const float* __restrict__ Mp,
                                                  float* __restrict__ Mt) {
  int e = blockIdx.x * 256 + threadIdx.x;  // float4 index, 512*256 = 131072 total
  const float4* p = (const float4*)Mp;
  float4 v0 = p[e];
  float4 v1 = p[e + 131072];
  float4 v2 = p[e + 2 * 131072];
  float4 v3 = p[e + 3 * 131072];
  float4 r;
  r.x = v0.x + v1.x + v2.x + v3.x;
  r.y = v0.y + v1.y + v2.y + v3.y;
  r.z = v0.z + v1.z + v2.z + v3.z;
  r.w = v0.w + v1.w + v2.w + v3.w;
  ((float4*)Mt)[e] = r;
}

// ---------------------------------------------------------------------------
// K3: out[b,k] = const[k] + sum_g Mt[g*256 + idx[b,g], k]
// One wave per row b; lane covers k and k+64. Mt rows are 512B contiguous.
// ---------------------------------------------------------------------------
__global__ __launch_bounds__(256) void k3_gather(const int* __restrict__ idxbuf,
                                                 const float* __restrict__ Mt,
                                                 const float* __restrict__ constv,
                                                 float* __restrict__ out) {
  const int t = threadIdx.x;
  const int w = t >> 6;
  const int lane = t & 63;
  const int b = blockIdx.x * 4 + w;
  float a0 = constv[lane];
  float a1 = constv[lane + 64];
  const int* ib = idxbuf + b * 16;
  int cg[16];
#pragma unroll
  for (int g = 0; g < 16; g++) cg[g] = g * 256 + ib[g];
#pragma unroll
  for (int g = 0; g < 16; g++) {
    const float* mrow = Mt + (size_t)cg[g] * 128;
    a0 += mrow[lane];
    a1 += mrow[lane + 64];
  }
  out[b * 128 + lane] = a0;
  out[b * 128 + lane + 64] = a1;
}

// ---------------------------------------------------------------------------
extern "C" void kernel_launch(void* const* d_in, const int* in_sizes, int n_in,
                              void* d_out, int out_size, void* d_ws, size_t ws_size,
                              hipStream_t stream) {
  const float* x  = (const float*)d_in[0];   // [32768,128]
  const float* W1 = (const float*)d_in[1];   // [4096,128]
  const float* b1 = (const float*)d_in[2];   // [4096]
  const float* W2 = (const float*)d_in[3];   // [4096,4096]
  const float* b2 = (const float*)d_in[4];   // [4096]
  const float* W3 = (const float*)d_in[5];   // [128,4096]
  const float* b3 = (const float*)d_in[6];   // [128]
  float* out = (float*)d_out;                // [32768,128]

  // workspace layout (all regions fully overwritten every call; total ~13 MB)
  char* w = (char*)d_ws;
  int* idxbuf          = (int*)(w);                          // 2 MB  [32768,16]
  unsigned short* W3b  = (unsigned short*)(w + (2u << 20));  // 1 MB  [128,4096] bf16
  float* Mp            = (float*)(w + (3u << 20));           // 8 MB  [4,4096,128]
  float* Mt            = (float*)(w + (11u << 20));          // 2 MB  [4096,128]
  float* constv        = (float*)(w + (13u << 20));          // 512 B [128]

  k0_cvt<<<256, 256, 0, stream>>>(W3, W3b);
  kconst<<<128, 64, 0, stream>>>(W3, b2, b3, constv);
  k1_gemm_argmax<<<dim3(512, 16), 256, 0, stream>>>(x, W1, b1, idxbuf);
  k2_mfma<<<dim3(256, 4), 64, 0, stream>>>(W2, W3b, Mp);
  k2b_reduce<<<512, 256, 0, stream>>>(Mp, Mt);
  k3_gather<<<8192, 256, 0, stream>>>(idxbuf, Mt, constv, out);
}

// Round 2
// 398.201 us; speedup vs baseline: 1.4792x; 1.4792x over previous
//
#include <hip/hip_runtime.h>
#include <cstdint>
#include <cstddef>

typedef __attribute__((ext_vector_type(8))) short bf16x8;
typedef __attribute__((ext_vector_type(4))) float f32x4;
typedef __attribute__((ext_vector_type(8))) unsigned short ushort8;

#define FIX_CAP 65536
#define MARGIN 1e-3f

__device__ __forceinline__ unsigned short f2bf(float f) {
  union { float f; unsigned int u; } x; x.f = f;
  unsigned int r = (x.u + 0x7fffu + ((x.u >> 16) & 1u)) >> 16;  // RNE
  return (unsigned short)r;
}
__device__ __forceinline__ float bf2f(unsigned short h) {
  union { unsigned int u; float f; } x; x.u = ((unsigned int)h) << 16;
  return x.f;
}

// ---------------------------------------------------------------------------
// kzero: zero Mt [4096,128] f32 and the fixup counter
// ---------------------------------------------------------------------------
__global__ __launch_bounds__(256) void kzero(float* __restrict__ Mt, int* __restrict__ cnt) {
  int e = blockIdx.x * 256 + threadIdx.x;  // 512*256 = 131072 float4s
  ((float4*)Mt)[e] = (float4){0.f, 0.f, 0.f, 0.f};
  if (e == 0) cnt[0] = 0;
}

// ---------------------------------------------------------------------------
// k0: W3 [128,4096] f32 -> bf16
// ---------------------------------------------------------------------------
__global__ __launch_bounds__(256) void k0_cvt(const float* __restrict__ W3,
                                              unsigned short* __restrict__ W3b) {
  int e = (blockIdx.x * 256 + threadIdx.x) * 8;
  float4 f0 = *(const float4*)(W3 + e);
  float4 f1 = *(const float4*)(W3 + e + 4);
  ushort8 v;
  v[0] = f2bf(f0.x); v[1] = f2bf(f0.y); v[2] = f2bf(f0.z); v[3] = f2bf(f0.w);
  v[4] = f2bf(f1.x); v[5] = f2bf(f1.y); v[6] = f2bf(f1.z); v[7] = f2bf(f1.w);
  *(ushort8*)(W3b + e) = v;
}

// ---------------------------------------------------------------------------
// kw1: W1 [4096,128] f32 -> hi/lo bf16 pair (row-major, for direct B-frags)
// ---------------------------------------------------------------------------
__global__ __launch_bounds__(256) void kw1_cvt(const float* __restrict__ W1,
                                               unsigned short* __restrict__ w1h,
                                               unsigned short* __restrict__ w1l) {
  int e = (blockIdx.x * 256 + threadIdx.x) * 8;
  float ff[8];
  *(float4*)&ff[0] = *(const float4*)(W1 + e);
  *(float4*)&ff[4] = *(const float4*)(W1 + e + 4);
  ushort8 h, l;
#pragma unroll
  for (int i = 0; i < 8; i++) {
    unsigned short hi = f2bf(ff[i]);
    h[i] = hi;
    l[i] = f2bf(ff[i] - bf2f(hi));
  }
  *(ushort8*)(w1h + e) = h;
  *(ushort8*)(w1l + e) = l;
}

// ---------------------------------------------------------------------------
// kconst: const[k] = dot(W3[k,:], b2) + b3[k]
// ---------------------------------------------------------------------------
__global__ __launch_bounds__(256) void kconst(const float* __restrict__ W3,
                                              const float* __restrict__ b2,
                                              const float* __restrict__ b3,
                                              float* __restrict__ constv) {
  __shared__ float red[4];
  int k = blockIdx.x;
  int t = threadIdx.x;
  float s = 0.f;
  for (int j = t; j < 4096; j += 256) s += W3[k * 4096 + j] * b2[j];
#pragma unroll
  for (int m = 1; m < 64; m <<= 1) s += __shfl_xor(s, m, 64);
  if ((t & 63) == 0) red[t >> 6] = s;
  __syncthreads();
  if (t == 0) constv[k] = red[0] + red[1] + red[2] + red[3] + b3[k];
}

// ---------------------------------------------------------------------------
// K1: o = x @ W1^T + b1 via bf16 MFMA 3-term split (xh*wh + xh*wl + xl*wh),
// fused per-segment top-2 argmax. Block = 64 rows x 256 cols (one segment),
// 4 waves; wave w covers 64 rows x 64 cols. x tile staged hi/lo in LDS
// (full K=128, single barrier). Near-ties (gap < MARGIN) flagged for exact
// fp32 fixup.
// ---------------------------------------------------------------------------
__global__ __launch_bounds__(256) void k1_mfma(
    const float* __restrict__ x, const unsigned short* __restrict__ w1h,
    const unsigned short* __restrict__ w1l, const float* __restrict__ b1,
    int* __restrict__ idxbuf, int* __restrict__ cnt, int* __restrict__ list) {
  __shared__ unsigned short xsh[64 * 136];  // stride 136 shorts: 2-way-free banks
  __shared__ unsigned short xsl[64 * 136];
  __shared__ float rv1[64 * 4];
  __shared__ int   ri1[64 * 4];
  __shared__ float rv2[64 * 4];

  const int t = threadIdx.x;
  const int r0 = blockIdx.x * 64;
  const int seg = blockIdx.y;

  // ---- stage x rows 64x128, on-the-fly hi/lo bf16 split ----
#pragma unroll
  for (int it = 0; it < 4; it++) {
    int ch = it * 256 + t;          // 1024 chunks of 8 elems
    int row = ch >> 4, k8 = ch & 15;
    float ff[8];
    *(float4*)&ff[0] = *(const float4*)(x + (r0 + row) * 128 + k8 * 8);
    *(float4*)&ff[4] = *(const float4*)(x + (r0 + row) * 128 + k8 * 8 + 4);
    ushort8 h, l;
#pragma unroll
    for (int i = 0; i < 8; i++) {
      unsigned short hi = f2bf(ff[i]);
      h[i] = hi;
      l[i] = f2bf(ff[i] - bf2f(hi));
    }
    *(ushort8*)&xsh[row * 136 + k8 * 8] = h;
    *(ushort8*)&xsl[row * 136 + k8 * 8] = l;
  }
  __syncthreads();

  const int lane = t & 63, wv = t >> 6;
  const int m = lane & 15, q = lane >> 4;
  const int cbase = seg * 256 + wv * 64;  // global col of (nt=0, n16=0)

  f32x4 acc[4][4];
#pragma unroll
  for (int mt = 0; mt < 4; mt++)
#pragma unroll
    for (int nt = 0; nt < 4; nt++) acc[mt][nt] = (f32x4){0.f, 0.f, 0.f, 0.f};

#pragma unroll
  for (int ks = 0; ks < 4; ks++) {
    const int k0 = ks * 32;
    bf16x8 ah[4], al[4];
#pragma unroll
    for (int mt = 0; mt < 4; mt++) {
      ah[mt] = *(const bf16x8*)&xsh[(mt * 16 + m) * 136 + k0 + q * 8];
      al[mt] = *(const bf16x8*)&xsl[(mt * 16 + m) * 136 + k0 + q * 8];
    }
#pragma unroll
    for (int nt = 0; nt < 4; nt++) {
      const size_t woff = (size_t)(cbase + nt * 16 + m) * 128 + k0 + q * 8;
      bf16x8 bh = *(const bf16x8*)(w1h + woff);
      bf16x8 bl = *(const bf16x8*)(w1l + woff);
#pragma unroll
      for (int mt = 0; mt < 4; mt++) {
        acc[mt][nt] = __builtin_amdgcn_mfma_f32_16x16x32_bf16(ah[mt], bh, acc[mt][nt], 0, 0, 0);
        acc[mt][nt] = __builtin_amdgcn_mfma_f32_16x16x32_bf16(ah[mt], bl, acc[mt][nt], 0, 0, 0);
        acc[mt][nt] = __builtin_amdgcn_mfma_f32_16x16x32_bf16(al[mt], bh, acc[mt][nt], 0, 0, 0);
      }
    }
  }

  // ---- bias + per-row top-2 (cols this wave: wv*64 .. wv*64+63 of segment) ----
  float bias[4];
#pragma unroll
  for (int nt = 0; nt < 4; nt++) bias[nt] = b1[cbase + nt * 16 + m];

#pragma unroll
  for (int mt = 0; mt < 4; mt++) {
#pragma unroll
    for (int reg = 0; reg < 4; reg++) {
      float v1 = acc[mt][0][reg] + bias[0];
      int i1 = wv * 64 + m;
      float v2 = -3.4e38f;
#pragma unroll
      for (int nt = 1; nt < 4; nt++) {
        float u = acc[mt][nt][reg] + bias[nt];
        int j = wv * 64 + nt * 16 + m;
        if (u > v1) { v2 = v1; v1 = u; i1 = j; } else { v2 = fmaxf(v2, u); }
      }
      // butterfly across the 16 lanes of this quarter (disjoint col sets)
#pragma unroll
      for (int msk = 1; msk <= 8; msk <<= 1) {
        float u1 = __shfl_xor(v1, msk, 64);
        int   j1 = __shfl_xor(i1, msk, 64);
        float u2 = __shfl_xor(v2, msk, 64);
        if (u1 > v1) { v2 = fmaxf(v1, u2); v1 = u1; i1 = j1; }
        else if (u1 == v1) { i1 = min(i1, j1); v2 = v1; }
        else { v2 = fmaxf(v2, u1); }
      }
      if (m == 0) {
        int rl = mt * 16 + q * 4 + reg;
        rv1[rl * 4 + wv] = v1; ri1[rl * 4 + wv] = i1; rv2[rl * 4 + wv] = v2;
      }
    }
  }
  __syncthreads();

  // ---- merge the 4 waves (disjoint 64-col ranges), emit idx + near-tie flag ----
  if (t < 64) {
    float v1 = rv1[t * 4], v2 = rv2[t * 4];
    int i1 = ri1[t * 4];
#pragma unroll
    for (int w = 1; w < 4; w++) {
      float u1 = rv1[t * 4 + w], u2 = rv2[t * 4 + w];
      int j1 = ri1[t * 4 + w];
      if (u1 > v1) { v2 = fmaxf(v1, u2); v1 = u1; i1 = j1; }
      else if (u1 == v1) { i1 = min(i1, j1); v2 = v1; }
      else { v2 = fmaxf(v2, u1); }
    }
    int b = r0 + t;
    idxbuf[b * 16 + seg] = i1;
    if (v1 - v2 < MARGIN) {
      int p = atomicAdd(cnt, 1);
      if (p < FIX_CAP) list[p] = (b << 4) | seg;
    }
  }
}

// ---------------------------------------------------------------------------
// K1fix: for flagged (b,seg), recompute all 256 logits in EXACT baseline fp32
// order (acc = b1[c]; ascending-k fmaf) — one column per thread — and take
// the argmax with lowest-index tie-break. Reproduces the proven-passing
// round-1 numerics on near-tie segments.
// ---------------------------------------------------------------------------
__global__ __launch_bounds__(256) void k1_fix(
    const float* __restrict__ x, const float* __restrict__ W1,
    const float* __restrict__ b1, const int* __restrict__ cnt,
    const int* __restrict__ list, int* __restrict__ idxbuf) {
  __shared__ float redv[4];
  __shared__ int   redi[4];
  const int t = threadIdx.x;
  const int lane = t & 63, wv = t >> 6;
  int n = cnt[0]; if (n > FIX_CAP) n = FIX_CAP;
  for (int e = blockIdx.x; e < n; e += 256) {
    int pk = list[e];
    int b = pk >> 4, seg = pk & 15;
    int c = seg * 256 + t;
    float a = b1[c];
    const float4* xr = (const float4*)(x + b * 128);   // broadcast reads
    const float4* wr = (const float4*)(W1 + (size_t)c * 128);
#pragma unroll 8
    for (int k4 = 0; k4 < 32; k4++) {
      float4 xv = xr[k4];
      float4 wv4 = wr[k4];
      a = fmaf(xv.x, wv4.x, a);
      a = fmaf(xv.y, wv4.y, a);
      a = fmaf(xv.z, wv4.z, a);
      a = fmaf(xv.w, wv4.w, a);
    }
    // argmax over 256 threads, lowest-index tie-break
    float v = a; int li = t;
#pragma unroll
    for (int msk = 1; msk < 64; msk <<= 1) {
      float u = __shfl_xor(v, msk, 64);
      int ju = __shfl_xor(li, msk, 64);
      if (u > v || (u == v && ju < li)) { v = u; li = ju; }
    }
    if (lane == 0) { redv[wv] = v; redi[wv] = li; }
    __syncthreads();
    if (t == 0) {
      float bv = redv[0]; int bi = redi[0];
#pragma unroll
      for (int w = 1; w < 4; w++) {
        if (redv[w] > bv || (redv[w] == bv && redi[w] < bi)) { bv = redv[w]; bi = redi[w]; }
      }
      idxbuf[b * 16 + seg] = bi;
    }
    __syncthreads();
  }
}

// ---------------------------------------------------------------------------
// K2: Mt[c,k] += sum_{j in chunk} W2[j,c]*W3[k,j] via bf16 MFMA, split-K=8,
// 4 waves/block, atomic f32 accumulate into zeroed Mt (order jitter ~1e-7).
// ---------------------------------------------------------------------------
__global__ __launch_bounds__(256) void k2_mfma(const float* __restrict__ W2,
                                               const unsigned short* __restrict__ W3b,
                                               float* __restrict__ Mt) {
  const int t = threadIdx.x;
  const int lane = t & 63, wv = t >> 6;
  const int c0 = (blockIdx.x * 4 + wv) * 16;  // 64 blocks * 4 waves -> 4096 c
  const int jq = blockIdx.y;                  // 8 K-chunks of 512
  const int m = lane & 15, q = lane >> 4;
  f32x4 acc[8];
#pragma unroll
  for (int nt = 0; nt < 8; nt++) acc[nt] = (f32x4){0.f, 0.f, 0.f, 0.f};

  for (int it = 0; it < 16; it++) {
    const int j0 = jq * 512 + it * 32;
    union { bf16x8 v; unsigned short u[8]; } a;
    const float* ap = W2 + (size_t)(j0 + q * 8) * 4096 + c0 + m;
#pragma unroll
    for (int i = 0; i < 8; i++) a.u[i] = f2bf(ap[(size_t)i * 4096]);
#pragma unroll
    for (int nt = 0; nt < 8; nt++) {
      bf16x8 b = *(const bf16x8*)(W3b + (nt * 16 + m) * 4096 + j0 + q * 8);
      acc[nt] = __builtin_amdgcn_mfma_f32_16x16x32_bf16(a.v, b, acc[nt], 0, 0, 0);
    }
  }
#pragma unroll
  for (int nt = 0; nt < 8; nt++)
#pragma unroll
    for (int r = 0; r < 4; r++)
      atomicAdd(&Mt[(size_t)(c0 + q * 4 + r) * 128 + nt * 16 + m], acc[nt][r]);
}

// ---------------------------------------------------------------------------
// K3: out[b,k] = const[k] + sum_g Mt[g*256 + idx[b,g], k]
// ---------------------------------------------------------------------------
__global__ __launch_bounds__(256) void k3_gather(const int* __restrict__ idxbuf,
                                                 const float* __restrict__ Mt,
                                                 const float* __restrict__ constv,
                                                 float* __restrict__ out) {
  const int t = threadIdx.x;
  const int w = t >> 6;
  const int lane = t & 63;
  const int b = blockIdx.x * 4 + w;
  float a0 = constv[lane];
  float a1 = constv[lane + 64];
  const int* ib = idxbuf + b * 16;
  int cg[16];
#pragma unroll
  for (int g = 0; g < 16; g++) cg[g] = g * 256 + ib[g];
#pragma unroll
  for (int g = 0; g < 16; g++) {
    const float* mrow = Mt + (size_t)cg[g] * 128;
    a0 += mrow[lane];
    a1 += mrow[lane + 64];
  }
  out[b * 128 + lane] = a0;
  out[b * 128 + lane + 64] = a1;
}

// ---------------------------------------------------------------------------
extern "C" void kernel_launch(void* const* d_in, const int* in_sizes, int n_in,
                              void* d_out, int out_size, void* d_ws, size_t ws_size,
                              hipStream_t stream) {
  const float* x  = (const float*)d_in[0];   // [32768,128]
  const float* W1 = (const float*)d_in[1];   // [4096,128]
  const float* b1 = (const float*)d_in[2];   // [4096]
  const float* W2 = (const float*)d_in[3];   // [4096,4096]
  const float* b2 = (const float*)d_in[4];   // [4096]
  const float* W3 = (const float*)d_in[5];   // [128,4096]
  const float* b3 = (const float*)d_in[6];   // [128]
  float* out = (float*)d_out;                // [32768,128]

  // workspace layout (~7.3 MB, all regions rewritten every call)
  char* w = (char*)d_ws;
  int* idxbuf         = (int*)(w);                           // 2 MB  [32768,16]
  unsigned short* W3b = (unsigned short*)(w + (2u << 20));   // 1 MB  [128,4096] bf16
  float* Mt           = (float*)(w + (3u << 20));            // 2 MB  [4096,128] f32
  unsigned short* w1h = (unsigned short*)(w + (5u << 20));   // 1 MB  [4096,128] bf16 hi
  unsigned short* w1l = (unsigned short*)(w + (6u << 20));   // 1 MB  [4096,128] bf16 lo
  float* constv       = (float*)(w + (7u << 20));            // 512 B [128]
  int* cnt            = (int*)(w + (7u << 20) + 1024);       // 4 B
  int* fixlist        = (int*)(w + (7u << 20) + 4096);       // 256 KB

  kzero<<<512, 256, 0, stream>>>(Mt, cnt);
  k0_cvt<<<256, 256, 0, stream>>>(W3, W3b);
  kconst<<<128, 256, 0, stream>>>(W3, b2, b3, constv);
  kw1_cvt<<<256, 256, 0, stream>>>(W1, w1h, w1l);
  k1_mfma<<<dim3(512, 16), 256, 0, stream>>>(x, w1h, w1l, b1, idxbuf, cnt, fixlist);
  k1_fix<<<256, 256, 0, stream>>>(x, W1, b1, cnt, fixlist, idxbuf);
  k2_mfma<<<dim3(64, 8), 256, 0, stream>>>(W2, W3b, Mt);
  k3_gather<<<8192, 256, 0, stream>>>(idxbuf, Mt, constv, out);
}